// Round 5
// baseline (345.586 us; speedup 1.0000x reference)
//
#include <hip/hip_runtime.h>
#include <hip/hip_fp16.h>

#define ETA 0.15f
#define LAM 0.05f

typedef unsigned int uint32;
typedef __attribute__((ext_vector_type(8))) short short8;
typedef __attribute__((ext_vector_type(4))) float floatx4;
typedef __attribute__((ext_vector_type(2))) uint32 uint32x2;
typedef __attribute__((ext_vector_type(4))) _Float16 half4;

static const int BSZ = 32, LL = 8192, DD = 64;
static const int RTOT = BSZ * LL; // 262144 rows

// 13-tap coefficients of S^6, S = (1-2*lam)I + lam*(R+R^-1), lam=0.05
#define SC0 0.5811044375f
#define SC1 0.182631375f
#define SC2 0.024907734375f
#define SC3 0.0018309375f
#define SC4 7.603125e-5f
#define SC5 1.6875e-6f
#define SC6 1.5625e-8f

// workspace layout (bytes): transposed bf16 weights only
static const size_t W1T_OFF = 0;                        // [256][128] bf16 (n-major)
static const size_t W2T_OFF = W1T_OFF + 256 * 128 * 2;  // [64][256] bf16
static const size_t WQT_OFF = W2T_OFF + 64 * 256 * 2;   // [64][64] bf16

__device__ __forceinline__ unsigned short f2bf(float f) {
    uint32 u = __builtin_bit_cast(uint32, f);
    uint32 r = (u + 0x7FFFu + ((u >> 16) & 1u)) >> 16;
    return (unsigned short)r;
}
// packed RNE f32x2 -> bf16x2 (1 VALU op; same rounding as f2bf)
__device__ __forceinline__ uint32 cvtpk(float lo, float hi) {
    uint32 r;
    asm("v_cvt_pk_bf16_f32 %0, %1, %2" : "=v"(r) : "v"(lo), "v"(hi));
    return r;
}
__device__ __forceinline__ float fast_softplus(float x) {
    return fmaxf(x, 0.f) + __logf(1.f + __expf(-fabsf(x)));
}
__device__ __forceinline__ float fast_tanh(float x) {
    float t = __expf(-2.f * fabsf(x));
    float r = (1.f - t) / (1.f + t);
    return copysignf(r, x);
}

// ---------------- prep: zero energy, transpose weights to bf16 ----------------
__global__ void prep_kernel(const float* __restrict__ W1, const float* __restrict__ W2,
                            const float* __restrict__ Wq,
                            unsigned short* __restrict__ w1t, unsigned short* __restrict__ w2t,
                            unsigned short* __restrict__ wqt, float* __restrict__ energy) {
    int tid = blockIdx.x * blockDim.x + threadIdx.x;
    int nth = gridDim.x * blockDim.x;
    for (int i = tid; i < 256 * 128; i += nth) { int n = i >> 7, k = i & 127; w1t[i] = f2bf(W1[k * 256 + n]); }
    for (int i = tid; i < 64 * 256; i += nth) { int n = i >> 8, k = i & 255; w2t[i] = f2bf(W2[k * 64 + n]); }
    for (int i = tid; i < 64 * 64;  i += nth) { int n = i >> 6, k = i & 63;  wqt[i] = f2bf(Wq[k * 64 + n]); }
    if (tid < 32) energy[tid] = 0.f;
}

// ---------------- fused MLP + K=6 iterations + energy ----------------
// Round-3 proven structure (passed, 333us) with two semantics-preserving deltas:
// (1) A,B held in fp32 registers from staging through the GEMMs -- no phase-3
//     reload (identical values: inputs are immutable, same addresses).
// (2) GEMM1 sequential ht-tiles (identical indices to the dual-acc version) to
//     free the ~40 VGPRs that (1) keeps live.
// Everything else verbatim r3: 64-row output window, 80-row halo'd window,
// hidden split in 2 halves (Zs over Qs), d-only iteration with padded LDS
// exchange, 13-tap S^6 s-channel, same barriers. LDS 43.5KB -> 3 blocks/CU.
__global__ __launch_bounds__(256, 3) void fused_kernel(
    const float* __restrict__ A, const float* __restrict__ B, const float* __restrict__ Q,
    const float* __restrict__ b1, const float* __restrict__ b2, const float* __restrict__ bq,
    const unsigned short* __restrict__ w1t, const unsigned short* __restrict__ w2t,
    const unsigned short* __restrict__ wqt,
    float* __restrict__ outA, float* __restrict__ outB, float* __restrict__ energy) {
    __shared__ char lds[43584];
    unsigned short* Xs = (unsigned short*)(lds);          // [80][136] bf16 @ [0,21760)
    unsigned short* Qs = (unsigned short*)(lds + 21760);  // [80][72]  bf16 @ [21760,33280)
    unsigned short* Zs = (unsigned short*)(lds + 21760);  // [80][136] bf16 @ [21760,43520) (half-hidden, over Qs after B1)
    _Float16* muS = (_Float16*)(lds);                     // [80][68] fp16 @ [0,10880)   (over Xs after GEMM1h2)
    float* exb = (float*)(lds + 10880);                   // [2][2][16][68] f32 @ [10880,28288) (iter phase)
    float* sS  = (float*)(lds);                           // [80][68] f32 @ [0,21760)    (s phase, over muS/exb)
    float* esm = (float*)(lds + 43520);                   // [4] f32

    const int tid = threadIdx.x;
    const int lane = tid & 63;
    const int w = tid >> 6;       // wave id
    const int q4 = lane >> 4;
    const int l16 = lane & 15;
    const int g = tid >> 4;       // iter layout: row group (5 rows each)
    const int c4 = tid & 15;      // iter layout: col quad
    const int bb = blockIdx.y;
    const int s0 = blockIdx.x * 64;
    const size_t bbase = (size_t)bb * LL;

    // ---- prefetch GEMM3 weights + biases (global, no LDS dep) ----
    short8 wqf[2];
#pragma unroll
    for (int kt = 0; kt < 2; kt++)
        wqf[kt] = *(const short8*)&wqt[(w * 16 + l16) * 64 + kt * 32 + q4 * 8];
    const floatx4 b2q = *(const floatx4*)&b2[w * 16 + q4 * 4];
    const floatx4 bqq = *(const floatx4*)&bq[w * 16 + q4 * 4];

    // ---- phase 1: stage X=[A|B], Q as bf16; A,B kept fp32 in regs (iter layout) ----
    floatx4 av[5], bv[5];
    uint32* Xu = (uint32*)Xs; // row stride 68 dwords
    uint32* Qu = (uint32*)Qs; // row stride 36 dwords
#pragma unroll
    for (int i = 0; i < 5; i++) {
        int wr = g * 5 + i;
        int gl = (s0 + wr + LL - 8) & (LL - 1); // window starts at s0-8 (circular)
        size_t base = (bbase + gl) * 64 + c4 * 4;
        av[i] = *(const floatx4*)(A + base);
        bv[i] = *(const floatx4*)(B + base);
        floatx4 qv = *(const floatx4*)(Q + base);
        uint32x2 ua; ua.x = cvtpk(av[i].x, av[i].y); ua.y = cvtpk(av[i].z, av[i].w);
        uint32x2 ub; ub.x = cvtpk(bv[i].x, bv[i].y); ub.y = cvtpk(bv[i].z, bv[i].w);
        uint32x2 uq; uq.x = cvtpk(qv.x, qv.y);       uq.y = cvtpk(qv.z, qv.w);
        *(uint32x2*)&Xu[wr * 68 + c4 * 2] = ua;
        *(uint32x2*)&Xu[wr * 68 + 32 + c4 * 2] = ub;
        *(uint32x2*)&Qu[wr * 36 + c4 * 2] = uq;
    }
    __syncthreads(); // B0: staging complete

    // ---- GEMM3 (swapped): acc3[nt][r] = gate_pre[row=nt*16+l16][col=w*16+q4*4+r] ----
    floatx4 acc3[5];
#pragma unroll
    for (int nt = 0; nt < 5; nt++) acc3[nt] = (floatx4){0.f, 0.f, 0.f, 0.f};
    __builtin_amdgcn_s_setprio(1);
#pragma unroll
    for (int nt = 0; nt < 5; nt++)
#pragma unroll
        for (int kt = 0; kt < 2; kt++) {
            short8 aq = *(const short8*)&Qs[(nt * 16 + l16) * 72 + kt * 32 + q4 * 8];
            acc3[nt] = __builtin_amdgcn_mfma_f32_16x16x32_bf16(wqf[kt], aq, acc3[nt], 0, 0, 0);
        }
    __builtin_amdgcn_s_setprio(0);
    __syncthreads(); // B1: Qs reads done; Zs may overlay

    // ---- GEMM1/GEMM2 over 2 hidden halves of 128 (sequential ht for reg headroom) ----
    floatx4 acc2[5];
#pragma unroll
    for (int nt = 0; nt < 5; nt++) acc2[nt] = (floatx4){0.f, 0.f, 0.f, 0.f};
#pragma unroll
    for (int h = 0; h < 2; h++) {
#pragma unroll
        for (int ht = 0; ht < 2; ht++) {
            short8 wf[4];
#pragma unroll
            for (int kt = 0; kt < 4; kt++)
                wf[kt] = *(const short8*)&w1t[(h * 128 + w * 32 + ht * 16 + l16) * 128 + kt * 32 + q4 * 8];
            floatx4 acc[5];
#pragma unroll
            for (int nt = 0; nt < 5; nt++) acc[nt] = (floatx4){0.f, 0.f, 0.f, 0.f};
            __builtin_amdgcn_s_setprio(1);
#pragma unroll
            for (int kt = 0; kt < 4; kt++)
#pragma unroll
                for (int nt = 0; nt < 5; nt++) {
                    short8 xf = *(const short8*)&Xs[(nt * 16 + l16) * 136 + kt * 32 + q4 * 8];
                    acc[nt] = __builtin_amdgcn_mfma_f32_16x16x32_bf16(wf[kt], xf, acc[nt], 0, 0, 0);
                }
            __builtin_amdgcn_s_setprio(0);
            const floatx4 b1q = *(const floatx4*)&b1[h * 128 + w * 32 + ht * 16 + q4 * 4];
#pragma unroll
            for (int nt = 0; nt < 5; nt++) {
                uint32x2 uz;
                uz.x = cvtpk(fmaxf(acc[nt][0] + b1q.x, 0.f), fmaxf(acc[nt][1] + b1q.y, 0.f));
                uz.y = cvtpk(fmaxf(acc[nt][2] + b1q.z, 0.f), fmaxf(acc[nt][3] + b1q.w, 0.f));
                *(uint32x2*)&Zs[(nt * 16 + l16) * 136 + w * 32 + ht * 16 + q4 * 4] = uz;
            }
        }
        // GEMM2 A-frags for this half
        short8 w2f[4];
#pragma unroll
        for (int kt = 0; kt < 4; kt++)
            w2f[kt] = *(const short8*)&w2t[(w * 16 + l16) * 256 + h * 128 + kt * 32 + q4 * 8];
        __syncthreads(); // B2/B4: Zs half complete (all Xs reads of this half done too)
        __builtin_amdgcn_s_setprio(1);
#pragma unroll
        for (int nt = 0; nt < 5; nt++)
#pragma unroll
            for (int kt = 0; kt < 4; kt++) {
                short8 az = *(const short8*)&Zs[(nt * 16 + l16) * 136 + kt * 32 + q4 * 8];
                acc2[nt] = __builtin_amdgcn_mfma_f32_16x16x32_bf16(w2f[kt], az, acc2[nt], 0, 0, 0);
            }
        __builtin_amdgcn_s_setprio(0);
        if (h == 0) __syncthreads(); // B3: h0 Zs reads done before h1 overwrites
    }

    // ---- epilogue: mu -> LDS fp16 (muS over dead Xs; disjoint from Zs) ----
#pragma unroll
    for (int nt = 0; nt < 5; nt++) {
        half4 hm;
#pragma unroll
        for (int r = 0; r < 4; r++) {
            float sp = fast_softplus(acc2[nt][r] + ((const float*)&b2q)[r]);
            float gt = fast_tanh(acc3[nt][r] + ((const float*)&bqq)[r]);
            hm[r] = (_Float16)(sp * (1.f + 0.5f * gt));
        }
        *(half4*)&muS[(nt * 16 + l16) * 68 + w * 16 + q4 * 4] = hm;
    }
    __syncthreads(); // B5: mu ready; Zs dead (exb region free)

    // ---- phase 3: s/d form from HELD registers; K=6 iterations on d only ----
    floatx4 sv[5], dv[5], fv[5];
#pragma unroll
    for (int i = 0; i < 5; i++) {
        int wr = g * 5 + i;
        sv[i] = av[i] + bv[i];
        dv[i] = av[i] - bv[i];
        half4 m4 = *(const half4*)&muS[wr * 68 + c4 * 4];
        fv[i] = 1.f - (2.f * ETA) * __builtin_convertvector(m4, floatx4);
    }
#define EXD(p, t, gg) (exb + (((p) * 2 + (t)) * 16 + (gg)) * 68 + c4 * 4)
    for (int it = 0; it < 6; it++) {
#pragma unroll
        for (int i = 0; i < 5; i++) dv[i] *= fv[i];
        const int p = it & 1;
        *(floatx4*)EXD(p, 0, g) = dv[0];
        *(floatx4*)EXD(p, 1, g) = dv[4];
        __syncthreads();
        floatx4 dUp = (g > 0)  ? *(const floatx4*)EXD(p, 1, g - 1) : dv[0];
        floatx4 dDn = (g < 15) ? *(const floatx4*)EXD(p, 0, g + 1) : dv[4];
        floatx4 prev = dUp, cur = dv[0];
#pragma unroll
        for (int i = 0; i < 5; i++) {
            floatx4 nxt = (i < 4) ? dv[i + 1] : dDn;
            dv[i] = cur - LAM * (2.f * cur - prev - nxt);
            prev = cur; cur = nxt;
        }
    }
#undef EXD
    // ---- energy partial (needs fv, final dv) ----
    float e = 0.f;
#pragma unroll
    for (int i = 0; i < 5; i++) {
        int wr = g * 5 + i;
        if (wr >= 8 && wr < 72) {
            floatx4 d = dv[i];
            floatx4 qv = (1.f - fv[i]) * d * d; // (1-f) = 2*eta*mu
            e += qv.x + qv.y + qv.z + qv.w;
        }
    }
    e *= 0.25f / ETA; // 0.5 * sum(mu * d^2)

    // ---- s channel: s_out = S^6 s_in, direct 13-tap over LDS ----
    __syncthreads(); // B6: exb reads done; sS may overlay
#pragma unroll
    for (int i = 0; i < 5; i++)
        *(floatx4*)&sS[(g * 5 + i) * 68 + c4 * 4] = sv[i];
    __syncthreads(); // B7: s staged
    floatx4 srow[17];
    const int sbase = g * 5 - 6;
#pragma unroll
    for (int j = 0; j < 17; j++) {
        int rr = min(max(sbase + j, 0), 79); // clamped loads unused by guarded outputs
        srow[j] = *(const floatx4*)&sS[rr * 68 + c4 * 4];
    }
#pragma unroll
    for (int i = 0; i < 5; i++) {
        floatx4 sm = SC0 * srow[i + 6];
        sm += SC1 * (srow[i + 5] + srow[i + 7]);
        sm += SC2 * (srow[i + 4] + srow[i + 8]);
        sm += SC3 * (srow[i + 3] + srow[i + 9]);
        sm += SC4 * (srow[i + 2] + srow[i + 10]);
        sm += SC5 * (srow[i + 1] + srow[i + 11]);
        sm += SC6 * (srow[i + 0] + srow[i + 12]);
        sv[i] = sm;
    }

    // ---- store interior rows (window rows 8..71) ----
#pragma unroll
    for (int i = 0; i < 5; i++) {
        int wr = g * 5 + i;
        if (wr >= 8 && wr < 72) {
            size_t gidx = (bbase + s0 + (wr - 8)) * 64 + c4 * 4;
            *(floatx4*)(outA + gidx) = (sv[i] + dv[i]) * 0.5f;
            *(floatx4*)(outB + gidx) = (sv[i] - dv[i]) * 0.5f;
        }
    }
#pragma unroll
    for (int off = 32; off > 0; off >>= 1) e += __shfl_down(e, off, 64);
    if ((tid & 63) == 0) esm[tid >> 6] = e;
    __syncthreads();
    if (tid == 0) atomicAdd(energy + bb, esm[0] + esm[1] + esm[2] + esm[3]);
}

extern "C" void kernel_launch(void* const* d_in, const int* in_sizes, int n_in,
                              void* d_out, int out_size, void* d_ws, size_t ws_size,
                              hipStream_t stream) {
    const float* A  = (const float*)d_in[0];
    const float* B  = (const float*)d_in[1];
    const float* Q  = (const float*)d_in[2];
    const float* W1 = (const float*)d_in[3];
    const float* b1 = (const float*)d_in[4];
    const float* W2 = (const float*)d_in[5];
    const float* b2 = (const float*)d_in[6];
    const float* Wq = (const float*)d_in[7];
    const float* bq = (const float*)d_in[8];

    float* outA = (float*)d_out;
    float* outB = outA + (size_t)RTOT * 64;
    float* energy = outB + (size_t)RTOT * 64;

    char* ws = (char*)d_ws;
    unsigned short* w1t = (unsigned short*)(ws + W1T_OFF);
    unsigned short* w2t = (unsigned short*)(ws + W2T_OFF);
    unsigned short* wqt = (unsigned short*)(ws + WQT_OFF);

    hipLaunchKernelGGL(prep_kernel, dim3(64), dim3(256), 0, stream,
                       W1, W2, Wq, w1t, w2t, wqt, energy);
    hipLaunchKernelGGL(fused_kernel, dim3(LL / 64, BSZ), dim3(256), 0, stream,
                       A, B, Q, b1, b2, bq, w1t, w2t, wqt, outA, outB, energy);
}